// Round 1
// baseline (97.605 us; speedup 1.0000x reference)
//
#include <hip/hip_runtime.h>

// Problem constants (match reference)
#define N_NODES 100000
#define E_EDGES 1600000
#define HD 64
#define MAXSRC 8192   // capacity for edges with dst==2 (expected ~16)

// Pass 1: in-degree histogram over dst + collect sources of edges into node 2.
__global__ void deg_collect_kernel(const int* __restrict__ src,
                                   const int* __restrict__ dst,
                                   int* __restrict__ deg,
                                   int* __restrict__ count,
                                   int* __restrict__ srclist) {
    int tid = blockIdx.x * blockDim.x + threadIdx.x;
    int e4 = tid;                       // process 4 edges per thread via int4
    const int4* dst4 = (const int4*)dst;
    if (e4 < E_EDGES / 4) {
        int4 d = dst4[e4];
        atomicAdd(&deg[d.x], 1);
        atomicAdd(&deg[d.y], 1);
        atomicAdd(&deg[d.z], 1);
        atomicAdd(&deg[d.w], 1);
        int base = e4 * 4;
        if (d.x == 2) { int i = atomicAdd(count, 1); if (i < MAXSRC) srclist[i] = src[base + 0]; }
        if (d.y == 2) { int i = atomicAdd(count, 1); if (i < MAXSRC) srclist[i] = src[base + 1]; }
        if (d.z == 2) { int i = atomicAdd(count, 1); if (i < MAXSRC) srclist[i] = src[base + 2]; }
        if (d.w == 2) { int i = atomicAdd(count, 1); if (i < MAXSRC) srclist[i] = src[base + 3]; }
    }
}

// Pass 2: everything else, for node 2 only. One block of 64 threads (1 wave),
// thread j owns output channel j.
__global__ __launch_bounds__(64) void final_kernel(
    const float* __restrict__ x,
    const float* __restrict__ Wz, const float* __restrict__ bz,
    const float* __restrict__ Wh, const float* __restrict__ bh,
    const float* __restrict__ LzW, const float* __restrict__ Lzb,
    const float* __restrict__ LhW, const float* __restrict__ Lhb,
    const float* __restrict__ W1, const float* __restrict__ b1,
    const float* __restrict__ gamma_, const float* __restrict__ beta_,
    const float* __restrict__ rmean, const float* __restrict__ rvar,
    const float* __restrict__ W2, const float* __restrict__ b2,
    const int* __restrict__ deg, const int* __restrict__ count,
    const int* __restrict__ srclist,
    float* __restrict__ out) {
    const int j = threadIdx.x;
    __shared__ float s_cz[HD];
    __shared__ float s_ch[HD];
    __shared__ float s_r[HD];

    int K = *count;
    if (K > MAXSRC) K = MAXSRC;
    // deg histogram excludes the self-loop; reference deg = indeg + 1.
    const float dinv2 = rsqrtf((float)(deg[2] + 1));

    float accz = 0.f, acch = 0.f;
    // self-loop contribution: weight dinv2^2, row x[2]
    {
        const float w = dinv2 * dinv2;
        float hz = 0.f, hh = 0.f;
        #pragma unroll 8
        for (int k = 0; k < HD; ++k) {
            const float xv = x[2 * HD + k];
            hz += xv * Wz[k * HD + j];
            hh += xv * Wh[k * HD + j];
        }
        accz += w * hz;
        acch += w * hh;
    }
    // incoming edges of node 2
    for (int i = 0; i < K; ++i) {
        const int s = srclist[i];
        const float w = rsqrtf((float)(deg[s] + 1)) * dinv2;
        float hz = 0.f, hh = 0.f;
        #pragma unroll 8
        for (int k = 0; k < HD; ++k) {
            const float xv = x[(size_t)s * HD + k];
            hz += xv * Wz[k * HD + j];
            hh += xv * Wh[k * HD + j];
        }
        accz += w * hz;
        acch += w * hh;
    }
    s_cz[j] = accz + bz[j];
    s_ch[j] = acch + bh[j];
    __syncthreads();

    // Gate linears: cat[c, H0] @ L*_W ; H0 = 0 so only first HD rows matter.
    float zdot = Lzb[j], hdot = Lhb[j];
    #pragma unroll 8
    for (int k = 0; k < HD; ++k) {
        zdot += s_cz[k] * LzW[k * HD + j];
        hdot += s_ch[k] * LhW[k * HD + j];
    }
    const float Zv = 1.f / (1.f + expf(-zdot));
    const float Ht = tanhf(hdot);
    const float h = (1.f - Zv) * Ht;     // Z*H0 + (1-Z)*Ht, H0=0
    s_r[j] = fmaxf(h, 0.f);              // relu
    __syncthreads();

    // MLP layer 1 + BatchNorm(eval) + relu
    float y1 = b1[j];
    #pragma unroll 8
    for (int k = 0; k < HD; ++k) y1 += s_r[k] * W1[k * HD + j];
    const float bn = (y1 - rmean[j]) * rsqrtf(rvar[j] + 1e-5f) * gamma_[j] + beta_[j];
    const float yr = fmaxf(bn, 0.f);

    // final projection to scalar: sum_j yr[j]*W2[j] + b2
    float part = yr * W2[j];
    #pragma unroll
    for (int off = 32; off > 0; off >>= 1)
        part += __shfl_down(part, off, 64);
    if (j == 0) out[0] = part + b2[0];
}

extern "C" void kernel_launch(void* const* d_in, const int* in_sizes, int n_in,
                              void* d_out, int out_size, void* d_ws, size_t ws_size,
                              hipStream_t stream) {
    const float* x     = (const float*)d_in[0];
    const float* Wz    = (const float*)d_in[1];
    const float* bz    = (const float*)d_in[2];
    // d_in[3]=Wr, d_in[4]=br: dead (R only scales H0==0)
    const float* Wh    = (const float*)d_in[5];
    const float* bh    = (const float*)d_in[6];
    const float* LzW   = (const float*)d_in[7];
    const float* Lzb   = (const float*)d_in[8];
    // d_in[9]=Lr_W, d_in[10]=Lr_b: dead
    const float* LhW   = (const float*)d_in[11];
    const float* Lhb   = (const float*)d_in[12];
    const float* W1    = (const float*)d_in[13];
    const float* b1    = (const float*)d_in[14];
    const float* gam   = (const float*)d_in[15];
    const float* bet   = (const float*)d_in[16];
    const float* rmean = (const float*)d_in[17];
    const float* rvar  = (const float*)d_in[18];
    const float* W2    = (const float*)d_in[19];
    const float* b2    = (const float*)d_in[20];
    const int*   src   = (const int*)d_in[21];
    const int*   dst   = (const int*)d_in[22];

    // ws layout: [count:16 ints][srclist:MAXSRC ints][deg:N ints]
    int* count   = (int*)d_ws;
    int* srclist = count + 16;
    int* deg     = srclist + MAXSRC;
    const size_t zero_bytes = (size_t)(16 + MAXSRC + N_NODES) * sizeof(int);
    hipMemsetAsync(d_ws, 0, zero_bytes, stream);

    const int nthreads = 256;
    const int work = E_EDGES / 4;
    const int nblocks = (work + nthreads - 1) / nthreads;
    deg_collect_kernel<<<nblocks, nthreads, 0, stream>>>(src, dst, deg, count, srclist);

    final_kernel<<<1, 64, 0, stream>>>(x, Wz, bz, Wh, bh, LzW, Lzb, LhW, Lhb,
                                       W1, b1, gam, bet, rmean, rvar, W2, b2,
                                       deg, count, srclist, (float*)d_out);
}

// Round 2
// 40.467 us; speedup vs baseline: 2.4120x; 2.4120x over previous
//
#include <hip/hip_runtime.h>

// Problem constants (match reference)
#define N_NODES 100000
#define E_EDGES 1600000
#define HD 64
#define CAP 128       // capacity for edges with dst==2 (expected ~16, Poisson(16))

// Pass 1: collect source nodes of edges into node 2. No histogram.
__global__ void collect_kernel(const int* __restrict__ src,
                               const int* __restrict__ dst,
                               int* __restrict__ count,
                               int* __restrict__ srclist) {
    int e4 = blockIdx.x * blockDim.x + threadIdx.x;
    const int4* dst4 = (const int4*)dst;
    if (e4 < E_EDGES / 4) {
        int4 d = dst4[e4];
        int base = e4 * 4;
        if (d.x == 2) { int i = atomicAdd(count, 1); if (i < CAP) srclist[i] = src[base + 0]; }
        if (d.y == 2) { int i = atomicAdd(count, 1); if (i < CAP) srclist[i] = src[base + 1]; }
        if (d.z == 2) { int i = atomicAdd(count, 1); if (i < CAP) srclist[i] = src[base + 2]; }
        if (d.w == 2) { int i = atomicAdd(count, 1); if (i < CAP) srclist[i] = src[base + 3]; }
    }
}

// Pass 2: in-degrees of only the K srclist nodes + node 2 (entry K).
// degs[i] = #edges with dst == ids[i].
__global__ void count_kernel(const int* __restrict__ dst,
                             const int* __restrict__ count,
                             const int* __restrict__ srclist,
                             int* __restrict__ degs) {
    __shared__ int ids[CAP + 1];
    __shared__ int cnt[CAP + 1];
    int K = *count; if (K > CAP) K = CAP;
    const int tot = K + 1;
    for (int i = threadIdx.x; i < tot; i += blockDim.x) {
        ids[i] = (i < K) ? srclist[i] : 2;
        cnt[i] = 0;
    }
    __syncthreads();
    const int4* dst4 = (const int4*)dst;
    const int stride = gridDim.x * blockDim.x;
    for (int e4 = blockIdx.x * blockDim.x + threadIdx.x; e4 < E_EDGES / 4; e4 += stride) {
        int4 d = dst4[e4];
        #pragma unroll 4
        for (int i = 0; i < tot; ++i) {
            const int id = ids[i];
            int m = (d.x == id) + (d.y == id) + (d.z == id) + (d.w == id);
            if (m) atomicAdd(&cnt[i], m);
        }
    }
    __syncthreads();
    for (int i = threadIdx.x; i < tot; i += blockDim.x)
        if (cnt[i]) atomicAdd(&degs[i], cnt[i]);
}

// Pass 3: everything else, for node 2 only. One block of 64 threads (1 wave),
// thread j owns output channel j.
__global__ __launch_bounds__(64) void final_kernel(
    const float* __restrict__ x,
    const float* __restrict__ Wz, const float* __restrict__ bz,
    const float* __restrict__ Wh, const float* __restrict__ bh,
    const float* __restrict__ LzW, const float* __restrict__ Lzb,
    const float* __restrict__ LhW, const float* __restrict__ Lhb,
    const float* __restrict__ W1, const float* __restrict__ b1,
    const float* __restrict__ gamma_, const float* __restrict__ beta_,
    const float* __restrict__ rmean, const float* __restrict__ rvar,
    const float* __restrict__ W2, const float* __restrict__ b2,
    const int* __restrict__ count, const int* __restrict__ srclist,
    const int* __restrict__ degs,
    float* __restrict__ out) {
    const int j = threadIdx.x;
    __shared__ float s_cz[HD];
    __shared__ float s_ch[HD];
    __shared__ float s_r[HD];

    int K = *count; if (K > CAP) K = CAP;
    // degs counts in-edges only; reference deg = indeg + 1 (self-loop).
    const float dinv2 = rsqrtf((float)(degs[K] + 1));

    float accz = 0.f, acch = 0.f;
    // self-loop contribution: weight dinv2^2, row x[2]
    {
        const float w = dinv2 * dinv2;
        float hz = 0.f, hh = 0.f;
        #pragma unroll 8
        for (int k = 0; k < HD; ++k) {
            const float xv = x[2 * HD + k];
            hz += xv * Wz[k * HD + j];
            hh += xv * Wh[k * HD + j];
        }
        accz += w * hz;
        acch += w * hh;
    }
    // incoming edges of node 2
    for (int i = 0; i < K; ++i) {
        const int s = srclist[i];
        const float w = rsqrtf((float)(degs[i] + 1)) * dinv2;
        float hz = 0.f, hh = 0.f;
        #pragma unroll 8
        for (int k = 0; k < HD; ++k) {
            const float xv = x[(size_t)s * HD + k];
            hz += xv * Wz[k * HD + j];
            hh += xv * Wh[k * HD + j];
        }
        accz += w * hz;
        acch += w * hh;
    }
    s_cz[j] = accz + bz[j];
    s_ch[j] = acch + bh[j];
    __syncthreads();

    // Gate linears: cat[c, H0] @ L*_W ; H0 = 0 so only first HD rows matter.
    float zdot = Lzb[j], hdot = Lhb[j];
    #pragma unroll 8
    for (int k = 0; k < HD; ++k) {
        zdot += s_cz[k] * LzW[k * HD + j];
        hdot += s_ch[k] * LhW[k * HD + j];
    }
    const float Zv = 1.f / (1.f + expf(-zdot));
    const float Ht = tanhf(hdot);
    const float h = (1.f - Zv) * Ht;     // Z*H0 + (1-Z)*Ht, H0=0
    s_r[j] = fmaxf(h, 0.f);              // relu
    __syncthreads();

    // MLP layer 1 + BatchNorm(eval) + relu
    float y1 = b1[j];
    #pragma unroll 8
    for (int k = 0; k < HD; ++k) y1 += s_r[k] * W1[k * HD + j];
    const float bn = (y1 - rmean[j]) * rsqrtf(rvar[j] + 1e-5f) * gamma_[j] + beta_[j];
    const float yr = fmaxf(bn, 0.f);

    // final projection to scalar: sum_j yr[j]*W2[j] + b2
    float part = yr * W2[j];
    #pragma unroll
    for (int off = 32; off > 0; off >>= 1)
        part += __shfl_down(part, off, 64);
    if (j == 0) out[0] = part + b2[0];
}

extern "C" void kernel_launch(void* const* d_in, const int* in_sizes, int n_in,
                              void* d_out, int out_size, void* d_ws, size_t ws_size,
                              hipStream_t stream) {
    const float* x     = (const float*)d_in[0];
    const float* Wz    = (const float*)d_in[1];
    const float* bz    = (const float*)d_in[2];
    // d_in[3]=Wr, d_in[4]=br: dead (R only scales H0==0)
    const float* Wh    = (const float*)d_in[5];
    const float* bh    = (const float*)d_in[6];
    const float* LzW   = (const float*)d_in[7];
    const float* Lzb   = (const float*)d_in[8];
    // d_in[9]=Lr_W, d_in[10]=Lr_b: dead
    const float* LhW   = (const float*)d_in[11];
    const float* Lhb   = (const float*)d_in[12];
    const float* W1    = (const float*)d_in[13];
    const float* b1    = (const float*)d_in[14];
    const float* gam   = (const float*)d_in[15];
    const float* bet   = (const float*)d_in[16];
    const float* rmean = (const float*)d_in[17];
    const float* rvar  = (const float*)d_in[18];
    const float* W2    = (const float*)d_in[19];
    const float* b2    = (const float*)d_in[20];
    const int*   src   = (const int*)d_in[21];
    const int*   dst   = (const int*)d_in[22];

    // ws layout: [count:16 ints][srclist:CAP ints][degs:CAP+1 ints]
    int* count   = (int*)d_ws;
    int* srclist = count + 16;
    int* degs    = srclist + CAP;
    const size_t zero_bytes = (size_t)(16 + CAP + CAP + 1) * sizeof(int);
    hipMemsetAsync(d_ws, 0, zero_bytes, stream);

    const int nthreads = 256;
    const int work = E_EDGES / 4;                         // 400K int4 elements
    const int nblocks = (work + nthreads - 1) / nthreads; // 1563
    collect_kernel<<<nblocks, nthreads, 0, stream>>>(src, dst, count, srclist);
    count_kernel<<<1024, nthreads, 0, stream>>>(dst, count, srclist, degs);

    final_kernel<<<1, 64, 0, stream>>>(x, Wz, bz, Wh, bh, LzW, Lzb, LhW, Lhb,
                                       W1, b1, gam, bet, rmean, rvar, W2, b2,
                                       count, srclist, degs, (float*)d_out);
}

// Round 3
// 24.061 us; speedup vs baseline: 4.0566x; 1.6819x over previous
//
#include <hip/hip_runtime.h>

// Problem constants (match reference)
#define N_NODES 100000
#define E_EDGES 1600000
#define HD 64
#define CAP 128       // capacity for edges with dst==2 (indegree ~Poisson(16))

// Pass 1: collect source nodes of edges into node 2.
__global__ void collect_kernel(const int* __restrict__ src,
                               const int* __restrict__ dst,
                               int* __restrict__ count,
                               int* __restrict__ srclist) {
    int e4 = blockIdx.x * blockDim.x + threadIdx.x;
    const int4* dst4 = (const int4*)dst;
    if (e4 < E_EDGES / 4) {
        int4 d = dst4[e4];
        int base = e4 * 4;
        if (d.x == 2) { int i = atomicAdd(count, 1); if (i < CAP) srclist[i] = src[base + 0]; }
        if (d.y == 2) { int i = atomicAdd(count, 1); if (i < CAP) srclist[i] = src[base + 1]; }
        if (d.z == 2) { int i = atomicAdd(count, 1); if (i < CAP) srclist[i] = src[base + 2]; }
        if (d.w == 2) { int i = atomicAdd(count, 1); if (i < CAP) srclist[i] = src[base + 3]; }
    }
}

// Pass 2: in-degrees of only the K srclist nodes + node 2 (entry K).
__global__ void count_kernel(const int* __restrict__ dst,
                             const int* __restrict__ count,
                             const int* __restrict__ srclist,
                             int* __restrict__ degs) {
    __shared__ int ids[CAP + 1];
    __shared__ int cnt[CAP + 1];
    int K = *count; if (K > CAP) K = CAP;
    const int tot = K + 1;
    for (int i = threadIdx.x; i < tot; i += blockDim.x) {
        ids[i] = (i < K) ? srclist[i] : 2;
        cnt[i] = 0;
    }
    __syncthreads();
    const int4* dst4 = (const int4*)dst;
    const int stride = gridDim.x * blockDim.x;
    for (int e4 = blockIdx.x * blockDim.x + threadIdx.x; e4 < E_EDGES / 4; e4 += stride) {
        int4 d = dst4[e4];
        for (int i = 0; i < tot; ++i) {
            const int id = ids[i];
            int m = (d.x == id) + (d.y == id) + (d.z == id) + (d.w == id);
            if (m) atomicAdd(&cnt[i], m);
        }
    }
    __syncthreads();
    for (int i = threadIdx.x; i < tot; i += blockDim.x)
        if (cnt[i]) atomicAdd(&degs[i], cnt[i]);
}

// Pass 3: node-2-only forward. 256 threads = 4 waves; lane j owns channel j.
// Key: GCN is linear -> xsum = sum_i w_i * x[s_i] first, then one matvec per
// weight matrix; all weight columns prefetched to registers at entry.
__global__ __launch_bounds__(256) void final_kernel(
    const float* __restrict__ x,
    const float* __restrict__ Wz, const float* __restrict__ bz,
    const float* __restrict__ Wh, const float* __restrict__ bh,
    const float* __restrict__ LzW, const float* __restrict__ Lzb,
    const float* __restrict__ LhW, const float* __restrict__ Lhb,
    const float* __restrict__ W1, const float* __restrict__ b1,
    const float* __restrict__ gamma_, const float* __restrict__ beta_,
    const float* __restrict__ rmean, const float* __restrict__ rvar,
    const float* __restrict__ W2, const float* __restrict__ b2,
    const int* __restrict__ count, const int* __restrict__ srclist,
    const int* __restrict__ degs,
    float* __restrict__ out) {
    const int tid  = threadIdx.x;
    const int lane = tid & 63;
    const int w    = tid >> 6;          // wave id 0..3

    __shared__ float s_part[4][HD];
    __shared__ float s_xsum[HD];
    __shared__ float s_cz[HD], s_ch[HD];
    __shared__ float s_r[HD];

    // ---- Prefetch all weight columns into registers (data-independent) ----
    // Phase B weights: waves 0,1 -> Wz halves; waves 2,3 -> Wh halves.
    const float* WB = (w < 2) ? Wz : Wh;
    const float* WC = (w < 2) ? LzW : LhW;
    const int k0 = (w & 1) * 32;
    float wB[32], wC[32], wD[16];
    #pragma unroll
    for (int kk = 0; kk < 32; ++kk) wB[kk] = WB[(size_t)(k0 + kk) * HD + lane];
    #pragma unroll
    for (int kk = 0; kk < 32; ++kk) wC[kk] = WC[(size_t)(k0 + kk) * HD + lane];
    #pragma unroll
    for (int kk = 0; kk < 16; ++kk) wD[kk] = W1[(size_t)(w * 16 + kk) * HD + lane];

    int K = *count; if (K > CAP) K = CAP;
    // degs counts in-edges only; reference deg = indeg + 1 (self-loop).
    const float dinv2 = rsqrtf((float)(degs[K] + 1));

    // ---- Phase A: weighted sum of x rows (edges strided across waves) ----
    float px = 0.f;
    for (int i = w; i < K; i += 4) {
        const int s = srclist[i];
        const float wt = rsqrtf((float)(degs[i] + 1)) * dinv2;
        px += wt * x[(size_t)s * HD + lane];
    }
    if (w == 0) px += (dinv2 * dinv2) * x[2 * HD + lane];   // self-loop
    s_part[w][lane] = px;
    __syncthreads();
    if (w == 0)
        s_xsum[lane] = s_part[0][lane] + s_part[1][lane] + s_part[2][lane] + s_part[3][lane];
    __syncthreads();

    // ---- Phase B: cz = xsum@Wz + bz ; ch = xsum@Wh + bh ----
    {
        float acc = 0.f;
        #pragma unroll
        for (int kk = 0; kk < 32; ++kk) acc += s_xsum[k0 + kk] * wB[kk];
        s_part[w][lane] = acc;
    }
    __syncthreads();
    if (w == 0)      s_cz[lane] = s_part[0][lane] + s_part[1][lane] + bz[lane];
    else if (w == 1) s_ch[lane] = s_part[2][lane] + s_part[3][lane] + bh[lane];
    __syncthreads();

    // ---- Phase C: gate linears (H0 = 0 -> only first HD rows of L matter) ----
    {
        const float* c = (w < 2) ? s_cz : s_ch;
        float acc = 0.f;
        #pragma unroll
        for (int kk = 0; kk < 32; ++kk) acc += c[k0 + kk] * wC[kk];
        s_part[w][lane] = acc;
    }
    __syncthreads();
    if (w == 0) {
        const float zdot = s_part[0][lane] + s_part[1][lane] + Lzb[lane];
        const float hdot = s_part[2][lane] + s_part[3][lane] + Lhb[lane];
        const float Zv = 1.f / (1.f + expf(-zdot));
        const float Ht = tanhf(hdot);
        s_r[lane] = fmaxf((1.f - Zv) * Ht, 0.f);   // h = (1-Z)*Ht (H0=0), relu
    }
    __syncthreads();

    // ---- Phase D: y1 = relu_out @ W1, k-quarter per wave ----
    {
        float acc = 0.f;
        #pragma unroll
        for (int kk = 0; kk < 16; ++kk) acc += s_r[w * 16 + kk] * wD[kk];
        s_part[w][lane] = acc;
    }
    __syncthreads();

    // ---- Phase E: BN(eval) + relu + dot with W2 (wave 0) ----
    if (w == 0) {
        float y1 = s_part[0][lane] + s_part[1][lane] + s_part[2][lane] + s_part[3][lane] + b1[lane];
        const float bn = (y1 - rmean[lane]) * rsqrtf(rvar[lane] + 1e-5f) * gamma_[lane] + beta_[lane];
        const float yr = fmaxf(bn, 0.f);
        float part = yr * W2[lane];
        #pragma unroll
        for (int off = 32; off > 0; off >>= 1)
            part += __shfl_down(part, off, 64);
        if (lane == 0) out[0] = part + b2[0];
    }
}

extern "C" void kernel_launch(void* const* d_in, const int* in_sizes, int n_in,
                              void* d_out, int out_size, void* d_ws, size_t ws_size,
                              hipStream_t stream) {
    const float* x     = (const float*)d_in[0];
    const float* Wz    = (const float*)d_in[1];
    const float* bz    = (const float*)d_in[2];
    // d_in[3]=Wr, d_in[4]=br: dead (R only scales H0==0)
    const float* Wh    = (const float*)d_in[5];
    const float* bh    = (const float*)d_in[6];
    const float* LzW   = (const float*)d_in[7];
    const float* Lzb   = (const float*)d_in[8];
    // d_in[9]=Lr_W, d_in[10]=Lr_b: dead
    const float* LhW   = (const float*)d_in[11];
    const float* Lhb   = (const float*)d_in[12];
    const float* W1    = (const float*)d_in[13];
    const float* b1    = (const float*)d_in[14];
    const float* gam   = (const float*)d_in[15];
    const float* bet   = (const float*)d_in[16];
    const float* rmean = (const float*)d_in[17];
    const float* rvar  = (const float*)d_in[18];
    const float* W2    = (const float*)d_in[19];
    const float* b2    = (const float*)d_in[20];
    const int*   src   = (const int*)d_in[21];
    const int*   dst   = (const int*)d_in[22];

    // ws layout: [count:16 ints][srclist:CAP ints][degs:CAP+1 ints]
    int* count   = (int*)d_ws;
    int* srclist = count + 16;
    int* degs    = srclist + CAP;
    const size_t zero_bytes = (size_t)(16 + CAP + CAP + 1) * sizeof(int);
    hipMemsetAsync(d_ws, 0, zero_bytes, stream);

    const int nthreads = 256;
    const int work = E_EDGES / 4;                         // 400K int4 elements
    const int nblocks = (work + nthreads - 1) / nthreads; // 1563
    collect_kernel<<<nblocks, nthreads, 0, stream>>>(src, dst, count, srclist);
    count_kernel<<<1024, nthreads, 0, stream>>>(dst, count, srclist, degs);

    final_kernel<<<1, 256, 0, stream>>>(x, Wz, bz, Wh, bh, LzW, Lzb, LhW, Lhb,
                                        W1, b1, gam, bet, rmean, rvar, W2, b2,
                                        count, srclist, degs, (float*)d_out);
}